// Round 1
// baseline (1589.061 us; speedup 1.0000x reference)
//
#include <hip/hip_runtime.h>
#include <cstddef>

static constexpr int   NN      = 2048;
static constexpr int   TPB_B   = 256;   // build_cost block
static constexpr int   TPB     = 1024;  // main kernel block (16 waves)
static constexpr int   NWB     = TPB / 64;          // 16 waves/block
static constexpr int   NB      = 128;               // main grid blocks
static constexpr int   MAX_IT  = 100;
static constexpr float EPS     = 0.1f;
static constexpr float INV_EPS = 10.0f;
// logf(1/2048 + 1e-8)
static constexpr float LOG_AB  = -7.6245985063594f;
static constexpr float THRESH  = 0.1f;

#define ALOAD(p)     __hip_atomic_load((p),  __ATOMIC_RELAXED, __HIP_MEMORY_SCOPE_AGENT)
#define ASTORE(p, x) __hip_atomic_store((p), (x), __ATOMIC_RELAXED, __HIP_MEMORY_SCOPE_AGENT)

typedef unsigned long long u64;

// ---------------------------------------------------------------------------
// Cost matrix build + signal-region zeroing. C[i][j] = sum_d (x[i,d]-y[j,d])^2.
// (harness poisons ws with 0xAA before every call -> re-zero signals every
//  launch; kernel-end L2 writeback makes plain stores visible to bypass loads)
// ---------------------------------------------------------------------------
__global__ __launch_bounds__(TPB_B)
void build_cost(const float* __restrict__ x, const float* __restrict__ y,
                float* __restrict__ C, float* __restrict__ CT,
                unsigned* __restrict__ zz, int zcount,
                int c_aligned, int use_ct)
{
    __shared__ float xs[64][65];
    __shared__ float ys[64][65];
    const int t  = threadIdx.x;
    const int bi = blockIdx.y, bj = blockIdx.x;

    if (bi == 0) {                       // 32 blocks zero the region in parallel
        int per = (zcount + 31) / 32;
        int lo = bj * per;
        int hi = lo + per; if (hi > zcount) hi = zcount;
        for (int idx = lo + t; idx < hi; idx += TPB_B) zz[idx] = 0u;
    }

#pragma unroll
    for (int k = 0; k < 16; ++k) {
        int idx = t + TPB_B * k;
        int r = idx >> 6, c = idx & 63;
        xs[r][c] = x[(size_t)(bi * 64 + r) * 64 + c];
        ys[r][c] = y[(size_t)(bj * 64 + r) * 64 + c];
    }
    __syncthreads();

    const int ti0 = (t >> 4) * 4;
    const int tj0 = (t & 15) * 4;
    float acc[4][4] = {};
#pragma unroll 8
    for (int d = 0; d < 64; ++d) {
        float xv[4], yv[4];
#pragma unroll
        for (int k = 0; k < 4; ++k) xv[k] = xs[ti0 + k][d];
#pragma unroll
        for (int l = 0; l < 4; ++l) yv[l] = ys[tj0 + l][d];
#pragma unroll
        for (int k = 0; k < 4; ++k)
#pragma unroll
            for (int l = 0; l < 4; ++l) {
                float df = xv[k] - yv[l];
                acc[k][l] = fmaf(df, df, acc[k][l]);
            }
    }

#pragma unroll
    for (int k = 0; k < 4; ++k) {
        size_t off = (size_t)(bi * 64 + ti0 + k) * NN + bj * 64 + tj0;
        if (c_aligned) {
            *(float4*)(C + off) = make_float4(acc[k][0], acc[k][1], acc[k][2], acc[k][3]);
        } else {
            C[off + 0] = acc[k][0]; C[off + 1] = acc[k][1];
            C[off + 2] = acc[k][2]; C[off + 3] = acc[k][3];
        }
    }
    if (use_ct) {
#pragma unroll
        for (int l = 0; l < 4; ++l) {
            size_t off = (size_t)(bj * 64 + tj0 + l) * NN + bi * 64 + ti0;
            *(float4*)(CT + off) = make_float4(acc[0][l], acc[1][l], acc[2][l], acc[3][l]);
        }
    }
}

// ---------------------------------------------------------------------------
// Helpers
// ---------------------------------------------------------------------------
__device__ __forceinline__ void load_row32(const float* row, int lane,
                                           int aligned, float c[32])
{
    if (aligned) {
        const float4* r4 = (const float4*)row;
#pragma unroll
        for (int k = 0; k < 8; ++k) {
            float4 A = r4[lane + 64 * k];
            c[4*k+0] = A.x; c[4*k+1] = A.y; c[4*k+2] = A.z; c[4*k+3] = A.w;
        }
    } else {
#pragma unroll
        for (int k = 0; k < 8; ++k) {
            const float* p = row + 4 * (lane + 64 * k);
            c[4*k+0] = p[0]; c[4*k+1] = p[1]; c[4*k+2] = p[2]; c[4*k+3] = p[3];
        }
    }
}

__device__ __forceinline__ void lds_row32(const float* sv, int lane, float b[32])
{
    const float4* s4 = (const float4*)sv;
#pragma unroll
    for (int k = 0; k < 8; ++k) {
        float4 A = s4[lane + 64 * k];
        b[4*k+0] = A.x; b[4*k+1] = A.y; b[4*k+2] = A.z; b[4*k+3] = A.w;
    }
}

// wave-level lse of (b-c)*INV_EPS over 2048 elems; result on ALL lanes.
__device__ __forceinline__ float wave_lse(const float c[32], const float b[32])
{
    float M = b[0] - c[0];
#pragma unroll
    for (int k = 1; k < 32; ++k) M = fmaxf(M, b[k] - c[k]);
#pragma unroll
    for (int off = 1; off < 64; off <<= 1) M = fmaxf(M, __shfl_xor(M, off));
    float Ms = M * INV_EPS;
    float s = 0.0f;
#pragma unroll
    for (int k = 0; k < 32; ++k) s += __expf(fmaf(b[k] - c[k], INV_EPS, -Ms));
#pragma unroll
    for (int off = 1; off < 64; off <<= 1) s += __shfl_xor(s, off);
    return Ms + __logf(s);
}

// ---------------------------------------------------------------------------
// Main cooperative kernel — sync-lean restructure of the 736us kernel:
//   * per-wave DIRECT posts: lane 0 posts {ep|u} the moment its lse is done.
//     No LDS staging, no staging barrier; earliest waves' values start
//     propagating while slower waves still compute.
//   * block-local convergence: every thread keeps last epoch's 2 polled
//     values in registers, computes |delta| during the poll, wave-reduces,
//     and the break check is a barrier-free LDS-broadcast sum at loop top.
//     rotR/rotC signals + 2 spin polls + 2 barriers: GONE. Bit-identical
//     break timing (all blocks reduce identical values in identical order).
//   * sv double-buffer (svA=u, svB=v) -> only 2 __syncthreads per iteration
//     (down from 6), each immediately before a phase that reads the whole
//     broadcast buffer.
//   * per-wave diff partials parity-buffered (sdu/sdv[2][..]) so the top
//     check never races a fast wave's next-iteration write.
// Poll/post scheme itself unchanged: self-validating {epoch|f32} u64 entries,
// detection IS the data fetch, epoch>=ep accept, no fences (safe: one-epoch
// separation is enforced by the A->B->A dependency chain).
// Cm may alias out+1 (crow/ccol register-resident before any overwrite).
// ---------------------------------------------------------------------------
__global__ __launch_bounds__(TPB)
void sinkhorn_main(const float* Cm, const float* __restrict__ CT,
                   u64* __restrict__ valA, u64* __restrict__ valB,
                   u64* __restrict__ costb,
                   float* out, int c_aligned, int use_ct)
{
    __shared__ __align__(16) float svA[2048];   // u(ep) broadcast
    __shared__ __align__(16) float svB[2048];   // v(ep) broadcast
    __shared__ float sdu[2][NWB];               // per-wave |du| partials (parity)
    __shared__ float sdv[2][NWB];               // per-wave |dv| partials (parity)
    const int t = threadIdx.x, lane = t & 63, w = t >> 6, b = blockIdx.x;
    const int i = b * NWB + w;

    // loop-invariant C row / CT col -> registers
    float crow[32], ccol[32];
    load_row32(Cm + (size_t)i * NN, lane, c_aligned, crow);
    if (use_ct) {
        load_row32(CT + (size_t)i * NN, lane, 1, ccol);
    } else {
#pragma unroll
        for (int k = 0; k < 8; ++k)
#pragma unroll
            for (int kk = 0; kk < 4; ++kk)
                ccol[4*k+kk] = Cm[(size_t)(4 * (lane + 64 * k) + kk) * NN + i];
    }

    for (int k = t; k < 2048; k += TPB) svB[k] = 0.0f;   // v(0) = 0
    __syncthreads();

    float u_keep = 0.0f;
    float uo0 = 0.0f, uo1 = 0.0f, vo0 = 0.0f, vo1 = 0.0f; // prev-epoch polled vals
    float b32[32];
    const int base = 2 * t;

    for (int it = 0; it < MAX_IT; ++it) {
        const unsigned ep = (unsigned)(it + 1);

        // ---- convergence check of epoch `it` (barrier-free; uniform:
        //      identical values reduced in identical order in every block)
        if (it >= 1) {
            const int pp = (it - 1) & 1;
            float sd = 0.0f;
#pragma unroll
            for (int k = 0; k < NWB; ++k) sd += sdu[pp][k] + sdv[pp][k];
            if (sd < THRESH) break;   // state: u_keep=u(it), svB=v(it)
        }

        // ---- row compute: u(ep)_i from svB = v(it); post immediately
        lds_row32(svB, lane, b32);
        float lse   = wave_lse(crow, b32);
        float u_new = EPS * (LOG_AB - lse);          // wave-uniform
        if (lane == 0)
            ASTORE(&valA[i], ((u64)ep << 32) | __float_as_uint(u_new));
        u_keep = u_new;

        // ---- poll A -> svA = u(ep); diff vs prev epoch from registers
        {
            u64 d0, d1;
            for (;;) {
                d0 = ALOAD(&valA[base + 0]);
                d1 = ALOAD(&valA[base + 1]);
                if (((unsigned)(d0 >> 32) >= ep) & ((unsigned)(d1 >> 32) >= ep))
                    break;
            }
            float f0 = __uint_as_float((unsigned)d0);
            float f1 = __uint_as_float((unsigned)d1);
            ((float2*)svA)[t] = make_float2(f0, f1);
            float d = fabsf(f0 - uo0) + fabsf(f1 - uo1);
            uo0 = f0; uo1 = f1;
#pragma unroll
            for (int off = 1; off < 64; off <<= 1) d += __shfl_xor(d, off);
            if (lane == 0) sdu[it & 1][w] = d;
        }
        __syncthreads();

        // ---- col compute: v(ep)_j from svA = u(ep); post immediately
        lds_row32(svA, lane, b32);
        lse = wave_lse(ccol, b32);
        float v_new = EPS * (LOG_AB - lse);
        if (lane == 0)
            ASTORE(&valB[i], ((u64)ep << 32) | __float_as_uint(v_new));

        // ---- poll B -> svB = v(ep)
        {
            u64 d0, d1;
            for (;;) {
                d0 = ALOAD(&valB[base + 0]);
                d1 = ALOAD(&valB[base + 1]);
                if (((unsigned)(d0 >> 32) >= ep) & ((unsigned)(d1 >> 32) >= ep))
                    break;
            }
            float f0 = __uint_as_float((unsigned)d0);
            float f1 = __uint_as_float((unsigned)d1);
            ((float2*)svB)[t] = make_float2(f0, f1);
            float d = fabsf(f0 - vo0) + fabsf(f1 - vo1);
            vo0 = f0; vo1 = f1;
#pragma unroll
            for (int off = 1; off < 64; off <<= 1) d += __shfl_xor(d, off);
            if (lane == 0) sdv[it & 1][w] = d;
        }
        __syncthreads();
    }

    // ---- epilogue: pi = exp((u_i + v_j - C_ij)/eps), cost = sum(pi*C)
    float cpart = 0.0f;
    {
        lds_row32(svB, lane, b32);         // svB = final v
        const float ui = u_keep;           // own row's final u (wave-uniform)
        float* orow = out + 1 + (size_t)i * NN;
#pragma unroll
        for (int k = 0; k < 8; ++k) {
#pragma unroll
            for (int kk = 0; kk < 4; ++kk) {
                float cc = crow[4*k+kk];
                float p  = __expf((ui + b32[4*k+kk] - cc) * INV_EPS);
                cpart = fmaf(p, cc, cpart);
                orow[4 * (lane + 64 * k) + kk] = p;  // crow in regs: alias-safe
            }
        }
    }
#pragma unroll
    for (int off = 1; off < 64; off <<= 1) cpart += __shfl_xor(cpart, off);
    if (lane == 0) sdu[0][w] = cpart;
    __syncthreads();
    if (t == 0) {
        float pc = 0.0f;
#pragma unroll
        for (int k = 0; k < NWB; ++k) pc += sdu[0][k];
        ASTORE(&costb[b], (1ull << 32) | __float_as_uint(pc));
    }
    if (b == 0) {                          // block 0 gathers the cost total
        if (t < NB) {
            u64 h;
            for (;;) { h = ALOAD(&costb[t]); if (h >= (1ull << 32)) break; }
            float pc = __uint_as_float((unsigned)h);
#pragma unroll
            for (int off = 1; off < 64; off <<= 1) pc += __shfl_xor(pc, off);
            if (lane == 0) sdv[0][w] = pc;
        }
        __syncthreads();
        if (t == 0) out[0] = sdv[0][0] + sdv[0][1];
    }
}

// ---------------------------------------------------------------------------
extern "C" void kernel_launch(void* const* d_in, const int* in_sizes, int n_in,
                              void* d_out, int out_size, void* d_ws, size_t ws_size,
                              hipStream_t stream)
{
    (void)in_sizes; (void)n_in; (void)out_size;
    const float* x = (const float*)d_in[0];
    const float* y = (const float*)d_in[1];
    float* out = (float*)d_out;
    char*  ws  = (char*)d_ws;

    const size_t CB = (size_t)NN * NN * sizeof(float);   // 16 MiB
    // signals: valA(2048) valB(2048) costb(128) u64
    const int    ZU = 2048 + 2048 + 128;                 // 4224 u64
    const size_t ZB = (size_t)ZU * sizeof(u64);

    float *Cm, *CT; char* zz;
    int c_aligned, use_ct;
    if (ws_size >= 2 * CB + ZB) {             // preferred: C, CT, signals in ws
        Cm = (float*)ws; CT = (float*)(ws + CB); zz = ws + 2 * CB;
        c_aligned = 1; use_ct = 1;
    } else if (ws_size >= CB + ZB) {          // C in out+1, CT in ws
        Cm = out + 1; CT = (float*)ws; zz = ws + CB;
        c_aligned = 0; use_ct = 1;
    } else {                                  // C in out+1, no CT (strided)
        Cm = out + 1; CT = nullptr; zz = ws;
        c_aligned = 0; use_ct = 0;
    }
    u64* valA  = (u64*)zz;
    u64* valB  = valA + 2048;
    u64* costb = valB + 2048;
    int  zcount = ZU * 2;                     // u32 elements to zero

    hipLaunchKernelGGL(build_cost, dim3(32, 32), dim3(TPB_B), 0, stream,
                       x, y, Cm, CT, (unsigned*)zz, zcount, c_aligned, use_ct);

    const float* Cmc = Cm;
    const float* CTc = CT;
    void* args[] = { (void*)&Cmc, (void*)&CTc, (void*)&valA, (void*)&valB,
                     (void*)&costb, (void*)&out, (void*)&c_aligned,
                     (void*)&use_ct };
    hipLaunchCooperativeKernel((void*)sinkhorn_main, dim3(NB), dim3(TPB),
                               args, 0, stream);
}

// Round 2
// 771.947 us; speedup vs baseline: 2.0585x; 2.0585x over previous
//
#include <hip/hip_runtime.h>
#include <cstddef>

static constexpr int   NN      = 2048;
static constexpr int   TPB_B   = 256;   // build_cost block
static constexpr int   TPB     = 1024;  // main kernel block (16 waves)
static constexpr int   NWB     = TPB / 64;          // 16 waves/block
static constexpr int   NB      = 128;               // main grid blocks
static constexpr int   MAX_IT  = 100;
static constexpr float EPS     = 0.1f;
static constexpr float INV_EPS = 10.0f;
// logf(1/2048 + 1e-8)
static constexpr float LOG_AB  = -7.6245985063594f;
static constexpr float THRESH  = 0.1f;

#define ALOAD(p)     __hip_atomic_load((p),  __ATOMIC_RELAXED, __HIP_MEMORY_SCOPE_AGENT)
#define ASTORE(p, x) __hip_atomic_store((p), (x), __ATOMIC_RELAXED, __HIP_MEMORY_SCOPE_AGENT)

typedef unsigned long long u64;

// ---------------------------------------------------------------------------
// Cost matrix build + signal-region zeroing. C[i][j] = sum_d (x[i,d]-y[j,d])^2.
// (harness poisons ws with 0xAA before every call -> re-zero signals every
//  launch; kernel-end L2 writeback makes plain stores visible to bypass loads)
// ---------------------------------------------------------------------------
__global__ __launch_bounds__(TPB_B)
void build_cost(const float* __restrict__ x, const float* __restrict__ y,
                float* __restrict__ C, float* __restrict__ CT,
                unsigned* __restrict__ zz, int zcount,
                int c_aligned, int use_ct)
{
    __shared__ float xs[64][65];
    __shared__ float ys[64][65];
    const int t  = threadIdx.x;
    const int bi = blockIdx.y, bj = blockIdx.x;

    if (bi == 0) {                       // 32 blocks zero the region in parallel
        int per = (zcount + 31) / 32;
        int lo = bj * per;
        int hi = lo + per; if (hi > zcount) hi = zcount;
        for (int idx = lo + t; idx < hi; idx += TPB_B) zz[idx] = 0u;
    }

#pragma unroll
    for (int k = 0; k < 16; ++k) {
        int idx = t + TPB_B * k;
        int r = idx >> 6, c = idx & 63;
        xs[r][c] = x[(size_t)(bi * 64 + r) * 64 + c];
        ys[r][c] = y[(size_t)(bj * 64 + r) * 64 + c];
    }
    __syncthreads();

    const int ti0 = (t >> 4) * 4;
    const int tj0 = (t & 15) * 4;
    float acc[4][4] = {};
#pragma unroll 8
    for (int d = 0; d < 64; ++d) {
        float xv[4], yv[4];
#pragma unroll
        for (int k = 0; k < 4; ++k) xv[k] = xs[ti0 + k][d];
#pragma unroll
        for (int l = 0; l < 4; ++l) yv[l] = ys[tj0 + l][d];
#pragma unroll
        for (int k = 0; k < 4; ++k)
#pragma unroll
            for (int l = 0; l < 4; ++l) {
                float df = xv[k] - yv[l];
                acc[k][l] = fmaf(df, df, acc[k][l]);
            }
    }

#pragma unroll
    for (int k = 0; k < 4; ++k) {
        size_t off = (size_t)(bi * 64 + ti0 + k) * NN + bj * 64 + tj0;
        if (c_aligned) {
            *(float4*)(C + off) = make_float4(acc[k][0], acc[k][1], acc[k][2], acc[k][3]);
        } else {
            C[off + 0] = acc[k][0]; C[off + 1] = acc[k][1];
            C[off + 2] = acc[k][2]; C[off + 3] = acc[k][3];
        }
    }
    if (use_ct) {
#pragma unroll
        for (int l = 0; l < 4; ++l) {
            size_t off = (size_t)(bj * 64 + tj0 + l) * NN + bi * 64 + ti0;
            *(float4*)(CT + off) = make_float4(acc[0][l], acc[1][l], acc[2][l], acc[3][l]);
        }
    }
}

// ---------------------------------------------------------------------------
// Helpers
// ---------------------------------------------------------------------------
__device__ __forceinline__ void load_row32(const float* row, int lane,
                                           int aligned, float c[32])
{
    if (aligned) {
        const float4* r4 = (const float4*)row;
#pragma unroll
        for (int k = 0; k < 8; ++k) {
            float4 A = r4[lane + 64 * k];
            c[4*k+0] = A.x; c[4*k+1] = A.y; c[4*k+2] = A.z; c[4*k+3] = A.w;
        }
    } else {
#pragma unroll
        for (int k = 0; k < 8; ++k) {
            const float* p = row + 4 * (lane + 64 * k);
            c[4*k+0] = p[0]; c[4*k+1] = p[1]; c[4*k+2] = p[2]; c[4*k+3] = p[3];
        }
    }
}

__device__ __forceinline__ void lds_row32(const float* sv, int lane, float b[32])
{
    const float4* s4 = (const float4*)sv;
#pragma unroll
    for (int k = 0; k < 8; ++k) {
        float4 A = s4[lane + 64 * k];
        b[4*k+0] = A.x; b[4*k+1] = A.y; b[4*k+2] = A.z; b[4*k+3] = A.w;
    }
}

// wave-level lse of (b-c)*INV_EPS over 2048 elems; result on ALL lanes.
__device__ __forceinline__ float wave_lse(const float c[32], const float b[32])
{
    float M = b[0] - c[0];
#pragma unroll
    for (int k = 1; k < 32; ++k) M = fmaxf(M, b[k] - c[k]);
#pragma unroll
    for (int off = 1; off < 64; off <<= 1) M = fmaxf(M, __shfl_xor(M, off));
    float Ms = M * INV_EPS;
    float s = 0.0f;
#pragma unroll
    for (int k = 0; k < 32; ++k) s += __expf(fmaf(b[k] - c[k], INV_EPS, -Ms));
#pragma unroll
    for (int off = 1; off < 64; off <<= 1) s += __shfl_xor(s, off);
    return Ms + __logf(s);
}

// ---------------------------------------------------------------------------
// Main cooperative kernel — the proven 736us structure (staged coalesced
// posts, self-validating {epoch|f32} u64 entries, detection IS the fetch,
// rot-deferred convergence, no fences), with ONE change: the convergence
// poll is moved from BEFORE post-A to AFTER post-A, so the rot round-trip
// (values posted one iteration ago; usually warm) overlaps A's propagation
// instead of delaying it, and its reduce barrier is FUSED with the poll-A
// barrier (6 -> 4 __syncthreads per iteration). Breaking after sv was
// overwritten with u(ep) is handled by restoring sv = v(it) from each
// thread's registers (vo0/vo1, kept from the previous poll-B) — the frozen
// state at break is bit-identical to the proven kernel: u_keep=u(it),
// sv=v(it), same break iteration (sd is reduced from identical values in
// identical order in every block).
// Cm may alias out+1 (crow/ccol register-resident before any overwrite).
// ---------------------------------------------------------------------------
__global__ __launch_bounds__(TPB)
void sinkhorn_main(const float* Cm, const float* __restrict__ CT,
                   u64* __restrict__ valA, u64* __restrict__ valB,
                   u64* __restrict__ rotR, u64* __restrict__ rotC,
                   u64* __restrict__ costb,
                   float* out, int c_aligned, int use_ct)
{
    __shared__ __align__(16) float sv[2048];
    __shared__ float swave[NWB];
    __shared__ float sdw[NWB];
    __shared__ float sred4[4];
    const int t = threadIdx.x, lane = t & 63, w = t >> 6, b = blockIdx.x;
    const int i = b * NWB + w;

    // loop-invariant C row / CT col -> registers
    float crow[32], ccol[32];
    load_row32(Cm + (size_t)i * NN, lane, c_aligned, crow);
    if (use_ct) {
        load_row32(CT + (size_t)i * NN, lane, 1, ccol);
    } else {
#pragma unroll
        for (int k = 0; k < 8; ++k)
#pragma unroll
            for (int kk = 0; kk < 4; ++kk)
                ccol[4*k+kk] = Cm[(size_t)(4 * (lane + 64 * k) + kk) * NN + i];
    }

    for (int k = t; k < 2048; k += TPB) sv[k] = 0.0f;   // v(0) = 0
    __syncthreads();

    float u_keep = 0.0f, v_keep = 0.0f;
    float vo0 = 0.0f, vo1 = 0.0f;        // prev-epoch v values (for break restore)
    float b32[32];
    const int base = 2 * t;

    for (int it = 0; it < MAX_IT; ++it) {
        const unsigned ep = (unsigned)(it + 1);

        // ---- row compute: u(ep)_i from sv = v(it)
        lds_row32(sv, lane, b32);
        float lse   = wave_lse(crow, b32);
        float u_new = EPS * (LOG_AB - lse);          // wave-uniform
        float pdr   = fabsf(u_new - u_keep);

        // ---- post A(ep): staged values (one 128B wave-store) + block pdiff
        if (lane == 0) { swave[w] = u_new; sdw[w] = pdr; }
        __syncthreads();                                            // S1
        if (t < NWB)
            ASTORE(&valA[b * NWB + t],
                   ((u64)ep << 32) | __float_as_uint(swave[t]));
        if (t == 0) {
            float ps = 0.0f;
#pragma unroll
            for (int k = 0; k < NWB; ++k) ps += sdw[k];
            ASTORE(&rotR[(ep & 3) * NB + b],
                   ((u64)ep << 32) | __float_as_uint(ps));
        }

        // ---- conv inputs of epoch `it` (posted last iteration; usually warm)
        //      polled WHILE A(ep) propagates — off the exchange critical path
        if (it >= 1 && t < NB) {                     // 128 threads, 2 waves
            u64 r1, r2;
            const int ri = (it & 3) * NB + t;
            for (;;) { r1 = ALOAD(&rotR[ri]);
                       if ((unsigned)(r1 >> 32) >= (unsigned)it) break; }
            for (;;) { r2 = ALOAD(&rotC[ri]);
                       if ((unsigned)(r2 >> 32) >= (unsigned)it) break; }
            float d = __uint_as_float((unsigned)r1) +
                      __uint_as_float((unsigned)r2);
#pragma unroll
            for (int off = 1; off < 64; off <<= 1) d += __shfl_xor(d, off);
            if (lane == 0) sred4[w] = d;
        }

        // ---- poll A -> sv = u(ep)  (detection IS the fetch)
        {
            u64 d0, d1;
            for (;;) {
                d0 = ALOAD(&valA[base + 0]);
                d1 = ALOAD(&valA[base + 1]);
                if (((unsigned)(d0 >> 32) >= ep) & ((unsigned)(d1 >> 32) >= ep))
                    break;
            }
            ((float2*)sv)[t] = make_float2(__uint_as_float((unsigned)d0),
                                           __uint_as_float((unsigned)d1));
        }
        __syncthreads();                                            // S2

        // ---- deferred convergence check of iteration `it`
        if (it >= 1) {
            float sd = sred4[0] + sred4[1];          // uniform across blocks
            if (sd < THRESH) {
                // restore sv = v(it) from registers; frozen state u(it), v(it)
                ((float2*)sv)[t] = make_float2(vo0, vo1);
                __syncthreads();
                break;
            }
        }
        u_keep = u_new;

        // ---- col compute: v(ep)_j from sv = u(ep)
        lds_row32(sv, lane, b32);
        lse = wave_lse(ccol, b32);
        float v_new = EPS * (LOG_AB - lse);
        float pdc   = fabsf(v_new - v_keep);
        v_keep = v_new;

        if (lane == 0) { swave[w] = v_new; sdw[w] = pdc; }
        __syncthreads();                                            // S3
        if (t < NWB)
            ASTORE(&valB[b * NWB + t],
                   ((u64)ep << 32) | __float_as_uint(swave[t]));
        if (t == 0) {
            float ps = 0.0f;
#pragma unroll
            for (int k = 0; k < NWB; ++k) ps += sdw[k];
            ASTORE(&rotC[(ep & 3) * NB + b],
                   ((u64)ep << 32) | __float_as_uint(ps));
        }
        // ---- poll B -> sv = v(ep)
        {
            u64 d0, d1;
            for (;;) {
                d0 = ALOAD(&valB[base + 0]);
                d1 = ALOAD(&valB[base + 1]);
                if (((unsigned)(d0 >> 32) >= ep) & ((unsigned)(d1 >> 32) >= ep))
                    break;
            }
            float f0 = __uint_as_float((unsigned)d0);
            float f1 = __uint_as_float((unsigned)d1);
            ((float2*)sv)[t] = make_float2(f0, f1);
            vo0 = f0; vo1 = f1;
        }
        __syncthreads();                                            // S4
    }

    // ---- epilogue: pi = exp((u_i + v_j - C_ij)/eps), cost = sum(pi*C)
    float cpart = 0.0f;
    {
        lds_row32(sv, lane, b32);          // sv = final v
        const float ui = u_keep;           // own row's final u (wave-uniform)
        float* orow = out + 1 + (size_t)i * NN;
#pragma unroll
        for (int k = 0; k < 8; ++k) {
#pragma unroll
            for (int kk = 0; kk < 4; ++kk) {
                float cc = crow[4*k+kk];
                float p  = __expf((ui + b32[4*k+kk] - cc) * INV_EPS);
                cpart = fmaf(p, cc, cpart);
                orow[4 * (lane + 64 * k) + kk] = p;  // crow in regs: alias-safe
            }
        }
    }
#pragma unroll
    for (int off = 1; off < 64; off <<= 1) cpart += __shfl_xor(cpart, off);
    if (lane == 0) sdw[w] = cpart;
    __syncthreads();
    if (t == 0) {
        float pc = 0.0f;
#pragma unroll
        for (int k = 0; k < NWB; ++k) pc += sdw[k];
        ASTORE(&costb[b], (1ull << 32) | __float_as_uint(pc));
    }
    if (b == 0) {                          // block 0 gathers the cost total
        if (t < NB) {
            u64 h;
            for (;;) { h = ALOAD(&costb[t]); if (h >= (1ull << 32)) break; }
            float pc = __uint_as_float((unsigned)h);
#pragma unroll
            for (int off = 1; off < 64; off <<= 1) pc += __shfl_xor(pc, off);
            if (lane == 0) sred4[w] = pc;
        }
        __syncthreads();
        if (t == 0) out[0] = sred4[0] + sred4[1];
    }
}

// ---------------------------------------------------------------------------
extern "C" void kernel_launch(void* const* d_in, const int* in_sizes, int n_in,
                              void* d_out, int out_size, void* d_ws, size_t ws_size,
                              hipStream_t stream)
{
    (void)in_sizes; (void)n_in; (void)out_size;
    const float* x = (const float*)d_in[0];
    const float* y = (const float*)d_in[1];
    float* out = (float*)d_out;
    char*  ws  = (char*)d_ws;

    const size_t CB = (size_t)NN * NN * sizeof(float);   // 16 MiB
    // signals: valA(2048) valB(2048) rotR(4*128) rotC(4*128) costb(128) u64
    const int    ZU = 2048 + 2048 + 512 + 512 + 128;     // 5248 u64
    const size_t ZB = (size_t)ZU * sizeof(u64);

    float *Cm, *CT; char* zz;
    int c_aligned, use_ct;
    if (ws_size >= 2 * CB + ZB) {             // preferred: C, CT, signals in ws
        Cm = (float*)ws; CT = (float*)(ws + CB); zz = ws + 2 * CB;
        c_aligned = 1; use_ct = 1;
    } else if (ws_size >= CB + ZB) {          // C in out+1, CT in ws
        Cm = out + 1; CT = (float*)ws; zz = ws + CB;
        c_aligned = 0; use_ct = 1;
    } else {                                  // C in out+1, no CT (strided)
        Cm = out + 1; CT = nullptr; zz = ws;
        c_aligned = 0; use_ct = 0;
    }
    u64* valA  = (u64*)zz;
    u64* valB  = valA + 2048;
    u64* rotR  = valB + 2048;
    u64* rotC  = rotR + 512;
    u64* costb = rotC + 512;
    int  zcount = ZU * 2;                     // u32 elements to zero

    hipLaunchKernelGGL(build_cost, dim3(32, 32), dim3(TPB_B), 0, stream,
                       x, y, Cm, CT, (unsigned*)zz, zcount, c_aligned, use_ct);

    const float* Cmc = Cm;
    const float* CTc = CT;
    void* args[] = { (void*)&Cmc, (void*)&CTc, (void*)&valA, (void*)&valB,
                     (void*)&rotR, (void*)&rotC, (void*)&costb,
                     (void*)&out, (void*)&c_aligned, (void*)&use_ct };
    hipLaunchCooperativeKernel((void*)sinkhorn_main, dim3(NB), dim3(TPB),
                               args, 0, stream);
}

// Round 3
// 728.151 us; speedup vs baseline: 2.1823x; 1.0601x over previous
//
#include <hip/hip_runtime.h>
#include <cstddef>

static constexpr int   NN      = 2048;
static constexpr int   TPB_B   = 256;   // build_cost block
static constexpr int   TPB     = 1024;  // main kernel block (16 waves)
static constexpr int   NWB     = TPB / 64;          // 16 waves/block
static constexpr int   NB      = 128;               // main grid blocks
static constexpr int   MAX_IT  = 100;
static constexpr float EPS     = 0.1f;
static constexpr float INV_EPS = 10.0f;
// logf(1/2048 + 1e-8)
static constexpr float LOG_AB  = -7.6245985063594f;
static constexpr float THRESH  = 0.1f;

#define ALOAD(p)     __hip_atomic_load((p),  __ATOMIC_RELAXED, __HIP_MEMORY_SCOPE_AGENT)
#define ASTORE(p, x) __hip_atomic_store((p), (x), __ATOMIC_RELAXED, __HIP_MEMORY_SCOPE_AGENT)

typedef unsigned long long u64;
typedef unsigned int u32x4 __attribute__((ext_vector_type(4)));

// 16B coherent poll load: one transaction instead of two 8B atomics.
// sc0 sc1 = system-scope bypass (>= agent): always reads past the XCD L2,
// same coherence point the 8B agent atomics used. Layout of the 16B:
// [val0][ep0][val1][ep1] (two {epoch<<32|f32} u64 entries, little-endian).
__device__ __forceinline__ u32x4 poll16(const u64* p)
{
    u32x4 q;
    asm volatile("global_load_dwordx4 %0, %1, off sc0 sc1\n\t"
                 "s_waitcnt vmcnt(0)"
                 : "=v"(q) : "v"(p) : "memory");
    return q;
}

__device__ __forceinline__ void post16(const u64* p, u32x4 s)
{
    asm volatile("global_store_dwordx4 %0, %1, off sc0 sc1"
                 :: "v"(p), "v"(s) : "memory");
}

// ---------------------------------------------------------------------------
// Cost matrix build + signal-region zeroing. C[i][j] = sum_d (x[i,d]-y[j,d])^2.
// (harness poisons ws with 0xAA before every call -> re-zero signals every
//  launch; kernel-end L2 writeback makes plain stores visible to bypass loads)
// ---------------------------------------------------------------------------
__global__ __launch_bounds__(TPB_B)
void build_cost(const float* __restrict__ x, const float* __restrict__ y,
                float* __restrict__ C, float* __restrict__ CT,
                unsigned* __restrict__ zz, int zcount,
                int c_aligned, int use_ct)
{
    __shared__ float xs[64][65];
    __shared__ float ys[64][65];
    const int t  = threadIdx.x;
    const int bi = blockIdx.y, bj = blockIdx.x;

    if (bi == 0) {                       // 32 blocks zero the region in parallel
        int per = (zcount + 31) / 32;
        int lo = bj * per;
        int hi = lo + per; if (hi > zcount) hi = zcount;
        for (int idx = lo + t; idx < hi; idx += TPB_B) zz[idx] = 0u;
    }

#pragma unroll
    for (int k = 0; k < 16; ++k) {
        int idx = t + TPB_B * k;
        int r = idx >> 6, c = idx & 63;
        xs[r][c] = x[(size_t)(bi * 64 + r) * 64 + c];
        ys[r][c] = y[(size_t)(bj * 64 + r) * 64 + c];
    }
    __syncthreads();

    const int ti0 = (t >> 4) * 4;
    const int tj0 = (t & 15) * 4;
    float acc[4][4] = {};
#pragma unroll 8
    for (int d = 0; d < 64; ++d) {
        float xv[4], yv[4];
#pragma unroll
        for (int k = 0; k < 4; ++k) xv[k] = xs[ti0 + k][d];
#pragma unroll
        for (int l = 0; l < 4; ++l) yv[l] = ys[tj0 + l][d];
#pragma unroll
        for (int k = 0; k < 4; ++k)
#pragma unroll
            for (int l = 0; l < 4; ++l) {
                float df = xv[k] - yv[l];
                acc[k][l] = fmaf(df, df, acc[k][l]);
            }
    }

#pragma unroll
    for (int k = 0; k < 4; ++k) {
        size_t off = (size_t)(bi * 64 + ti0 + k) * NN + bj * 64 + tj0;
        if (c_aligned) {
            *(float4*)(C + off) = make_float4(acc[k][0], acc[k][1], acc[k][2], acc[k][3]);
        } else {
            C[off + 0] = acc[k][0]; C[off + 1] = acc[k][1];
            C[off + 2] = acc[k][2]; C[off + 3] = acc[k][3];
        }
    }
    if (use_ct) {
#pragma unroll
        for (int l = 0; l < 4; ++l) {
            size_t off = (size_t)(bj * 64 + tj0 + l) * NN + bi * 64 + ti0;
            *(float4*)(CT + off) = make_float4(acc[0][l], acc[1][l], acc[2][l], acc[3][l]);
        }
    }
}

// ---------------------------------------------------------------------------
// Helpers
// ---------------------------------------------------------------------------
__device__ __forceinline__ void load_row32(const float* row, int lane,
                                           int aligned, float c[32])
{
    if (aligned) {
        const float4* r4 = (const float4*)row;
#pragma unroll
        for (int k = 0; k < 8; ++k) {
            float4 A = r4[lane + 64 * k];
            c[4*k+0] = A.x; c[4*k+1] = A.y; c[4*k+2] = A.z; c[4*k+3] = A.w;
        }
    } else {
#pragma unroll
        for (int k = 0; k < 8; ++k) {
            const float* p = row + 4 * (lane + 64 * k);
            c[4*k+0] = p[0]; c[4*k+1] = p[1]; c[4*k+2] = p[2]; c[4*k+3] = p[3];
        }
    }
}

__device__ __forceinline__ void lds_row32(const float* sv, int lane, float b[32])
{
    const float4* s4 = (const float4*)sv;
#pragma unroll
    for (int k = 0; k < 8; ++k) {
        float4 A = s4[lane + 64 * k];
        b[4*k+0] = A.x; b[4*k+1] = A.y; b[4*k+2] = A.z; b[4*k+3] = A.w;
    }
}

// wave-level lse of (b-c)*INV_EPS over 2048 elems; result on ALL lanes.
__device__ __forceinline__ float wave_lse(const float c[32], const float b[32])
{
    float M = b[0] - c[0];
#pragma unroll
    for (int k = 1; k < 32; ++k) M = fmaxf(M, b[k] - c[k]);
#pragma unroll
    for (int off = 1; off < 64; off <<= 1) M = fmaxf(M, __shfl_xor(M, off));
    float Ms = M * INV_EPS;
    float s = 0.0f;
#pragma unroll
    for (int k = 0; k < 32; ++k) s += __expf(fmaf(b[k] - c[k], INV_EPS, -Ms));
#pragma unroll
    for (int off = 1; off < 64; off <<= 1) s += __shfl_xor(s, off);
    return Ms + __logf(s);
}

// ---------------------------------------------------------------------------
// Main cooperative kernel — the proven 736us/652us structure, UNCHANGED in
// schedule (6 barriers/iter, rot-deferred conv check before post-A, staged
// coalesced posts, detection IS the fetch). Only the transaction shape of
// the value exchange changed:
//   * polls: one 16B dwordx4 sc0 sc1 load per thread (was 2x 8B atomic) ->
//     spin transactions per round halve (16K -> 8K grid-wide)
//   * posts: 8 lanes x 16B dwordx4 (was 16 lanes x 8B atomic)
//   * rot conv spins: both loads issued per round (was two serial loops)
// 16B snapshot safety: each {val,ep} pair is written by ONE 16B store, and
// entries remain individually self-validating, so any tear across the two
// u64s is caught by the epoch check (same guarantee as before).
// Cm may alias out+1 (crow/ccol register-resident before any overwrite).
// ---------------------------------------------------------------------------
__global__ __launch_bounds__(TPB)
void sinkhorn_main(const float* Cm, const float* __restrict__ CT,
                   u64* __restrict__ valA, u64* __restrict__ valB,
                   u64* __restrict__ rotR, u64* __restrict__ rotC,
                   u64* __restrict__ costb,
                   float* out, int c_aligned, int use_ct)
{
    __shared__ float sv[2048];
    __shared__ float swave[NWB];
    __shared__ float sdw[NWB];
    __shared__ float sred4[4];
    __shared__ float sdiff;
    const int t = threadIdx.x, lane = t & 63, w = t >> 6, b = blockIdx.x;
    const int i = b * NWB + w;

    // loop-invariant C row / CT col -> registers
    float crow[32], ccol[32];
    load_row32(Cm + (size_t)i * NN, lane, c_aligned, crow);
    if (use_ct) {
        load_row32(CT + (size_t)i * NN, lane, 1, ccol);
    } else {
#pragma unroll
        for (int k = 0; k < 8; ++k)
#pragma unroll
            for (int kk = 0; kk < 4; ++kk)
                ccol[4*k+kk] = Cm[(size_t)(4 * (lane + 64 * k) + kk) * NN + i];
    }

    for (int k = t; k < 2048; k += TPB) sv[k] = 0.0f;   // v(0) = 0
    __syncthreads();

    float u_keep = 0.0f, v_keep = 0.0f;
    float b32[32];

    for (int it = 0; it < MAX_IT; ++it) {
        const unsigned ep = (unsigned)(it + 1);

        // ---- row compute: u(ep)_i from sv = v(it)
        lds_row32(sv, lane, b32);
        float lse   = wave_lse(crow, b32);
        float u_new = EPS * (LOG_AB - lse);          // wave-uniform
        float pdr   = fabsf(u_new - u_keep);

        // ---- deferred convergence check of iteration `it` (epoch it)
        if (it >= 1) {
            if (t < NB) {                            // 128 threads, 2 waves
                u64 r1, r2;
                const int ri = (it & 3) * NB + t;
                for (;;) {
                    r1 = ALOAD(&rotR[ri]);
                    r2 = ALOAD(&rotC[ri]);
                    if (((unsigned)(r1 >> 32) >= (unsigned)it) &
                        ((unsigned)(r2 >> 32) >= (unsigned)it)) break;
                }
                float d = __uint_as_float((unsigned)r1) +
                          __uint_as_float((unsigned)r2);
#pragma unroll
                for (int off = 1; off < 64; off <<= 1) d += __shfl_xor(d, off);
                if (lane == 0) sred4[w] = d;
            }
            __syncthreads();
            if (t == 0) sdiff = sred4[0] + sred4[1];
            __syncthreads();
            if (sdiff < THRESH) break;   // state: u_keep=u(it), v_keep, sv=v(it)
        }
        u_keep = u_new;

        // ---- post A(ep): staged values (8x 16B wave-store) + block pdiff
        if (lane == 0) { swave[w] = u_new; sdw[w] = pdr; }
        __syncthreads();
        if (t < NWB / 2) {
            u32x4 s;
            s.x = __float_as_uint(swave[2*t + 0]); s.y = ep;
            s.z = __float_as_uint(swave[2*t + 1]); s.w = ep;
            post16(&valA[b * NWB + 2*t], s);
        }
        if (t == 0) {
            float ps = 0.0f;
#pragma unroll
            for (int k = 0; k < NWB; ++k) ps += sdw[k];
            ASTORE(&rotR[(ep & 3) * NB + b],
                   ((u64)ep << 32) | __float_as_uint(ps));
        }
        // ---- poll A -> sv = u(ep)  (detection IS the fetch; one 16B load)
        {
            u32x4 q;
            for (;;) {
                q = poll16(&valA[2 * t]);
                if ((q.y >= ep) & (q.w >= ep)) break;
            }
            ((float2*)sv)[t] = make_float2(__uint_as_float(q.x),
                                           __uint_as_float(q.z));
        }
        __syncthreads();

        // ---- col compute: v(ep)_j from sv = u(ep)
        lds_row32(sv, lane, b32);
        lse = wave_lse(ccol, b32);
        float v_new = EPS * (LOG_AB - lse);
        float pdc   = fabsf(v_new - v_keep);
        v_keep = v_new;

        if (lane == 0) { swave[w] = v_new; sdw[w] = pdc; }
        __syncthreads();
        if (t < NWB / 2) {
            u32x4 s;
            s.x = __float_as_uint(swave[2*t + 0]); s.y = ep;
            s.z = __float_as_uint(swave[2*t + 1]); s.w = ep;
            post16(&valB[b * NWB + 2*t], s);
        }
        if (t == 0) {
            float ps = 0.0f;
#pragma unroll
            for (int k = 0; k < NWB; ++k) ps += sdw[k];
            ASTORE(&rotC[(ep & 3) * NB + b],
                   ((u64)ep << 32) | __float_as_uint(ps));
        }
        // ---- poll B -> sv = v(ep)
        {
            u32x4 q;
            for (;;) {
                q = poll16(&valB[2 * t]);
                if ((q.y >= ep) & (q.w >= ep)) break;
            }
            ((float2*)sv)[t] = make_float2(__uint_as_float(q.x),
                                           __uint_as_float(q.z));
        }
        __syncthreads();
    }

    // ---- epilogue: pi = exp((u_i + v_j - C_ij)/eps), cost = sum(pi*C)
    float cpart = 0.0f;
    {
        lds_row32(sv, lane, b32);          // sv = final v
        const float ui = u_keep;           // own row's final u (wave-uniform)
        float* orow = out + 1 + (size_t)i * NN;
#pragma unroll
        for (int k = 0; k < 8; ++k) {
#pragma unroll
            for (int kk = 0; kk < 4; ++kk) {
                float cc = crow[4*k+kk];
                float p  = __expf((ui + b32[4*k+kk] - cc) * INV_EPS);
                cpart = fmaf(p, cc, cpart);
                orow[4 * (lane + 64 * k) + kk] = p;  // crow in regs: alias-safe
            }
        }
    }
#pragma unroll
    for (int off = 1; off < 64; off <<= 1) cpart += __shfl_xor(cpart, off);
    if (lane == 0) sdw[w] = cpart;
    __syncthreads();
    if (t == 0) {
        float pc = 0.0f;
#pragma unroll
        for (int k = 0; k < NWB; ++k) pc += sdw[k];
        ASTORE(&costb[b], (1ull << 32) | __float_as_uint(pc));
    }
    if (b == 0) {                          // block 0 gathers the cost total
        if (t < NB) {
            u64 h;
            for (;;) { h = ALOAD(&costb[t]); if (h >= (1ull << 32)) break; }
            float pc = __uint_as_float((unsigned)h);
#pragma unroll
            for (int off = 1; off < 64; off <<= 1) pc += __shfl_xor(pc, off);
            if (lane == 0) sred4[w] = pc;
        }
        __syncthreads();
        if (t == 0) out[0] = sred4[0] + sred4[1];
    }
}

// ---------------------------------------------------------------------------
extern "C" void kernel_launch(void* const* d_in, const int* in_sizes, int n_in,
                              void* d_out, int out_size, void* d_ws, size_t ws_size,
                              hipStream_t stream)
{
    (void)in_sizes; (void)n_in; (void)out_size;
    const float* x = (const float*)d_in[0];
    const float* y = (const float*)d_in[1];
    float* out = (float*)d_out;
    char*  ws  = (char*)d_ws;

    const size_t CB = (size_t)NN * NN * sizeof(float);   // 16 MiB
    // signals: valA(2048) valB(2048) rotR(4*128) rotC(4*128) costb(128) u64
    const int    ZU = 2048 + 2048 + 512 + 512 + 128;     // 5248 u64
    const size_t ZB = (size_t)ZU * sizeof(u64);

    float *Cm, *CT; char* zz;
    int c_aligned, use_ct;
    if (ws_size >= 2 * CB + ZB) {             // preferred: C, CT, signals in ws
        Cm = (float*)ws; CT = (float*)(ws + CB); zz = ws + 2 * CB;
        c_aligned = 1; use_ct = 1;
    } else if (ws_size >= CB + ZB) {          // C in out+1, CT in ws
        Cm = out + 1; CT = (float*)ws; zz = ws + CB;
        c_aligned = 0; use_ct = 1;
    } else {                                  // C in out+1, no CT (strided)
        Cm = out + 1; CT = nullptr; zz = ws;
        c_aligned = 0; use_ct = 0;
    }
    u64* valA  = (u64*)zz;
    u64* valB  = valA + 2048;
    u64* rotR  = valB + 2048;
    u64* rotC  = rotR + 512;
    u64* costb = rotC + 512;
    int  zcount = ZU * 2;                     // u32 elements to zero

    hipLaunchKernelGGL(build_cost, dim3(32, 32), dim3(TPB_B), 0, stream,
                       x, y, Cm, CT, (unsigned*)zz, zcount, c_aligned, use_ct);

    const float* Cmc = Cm;
    const float* CTc = CT;
    void* args[] = { (void*)&Cmc, (void*)&CTc, (void*)&valA, (void*)&valB,
                     (void*)&rotR, (void*)&rotC, (void*)&costb,
                     (void*)&out, (void*)&c_aligned, (void*)&use_ct };
    hipLaunchCooperativeKernel((void*)sinkhorn_main, dim3(NB), dim3(TPB),
                               args, 0, stream);
}